// Round 8
// baseline (584.017 us; speedup 1.0000x reference)
//
#include <hip/hip_runtime.h>

// SwinV2 window attention — round 8: FULL FUSION redux (round-2 structure,
// round-4 spill fix). Block = one window, wave = one head; qkv GEMM ->
// attention -> proj all in-register/LDS, no HBM intermediates.
// Round 2's 954us was a VGPR-64 spill artifact ((512,4) bound), not fusion cost.
// ws layout: [0,128K) biasfrag f32 | [128K,512K) w_t fp16[768][256]
//   | [512K,640K) p_t fp16[256][256]

typedef _Float16 f16;
typedef _Float16 f16x4 __attribute__((ext_vector_type(4)));
typedef _Float16 f16x8 __attribute__((ext_vector_type(8)));
typedef float f32x4 __attribute__((ext_vector_type(4)));

#define LOG100 4.6051701859880914f
#define EPS_L2 1.55e-5f

__device__ __forceinline__ int seg2(int p) { return (p >= 248) + (p >= 252); }

// ---------------- prep: CPB bias (MFMA C-frag order) + weight transpose/convert
__global__ __launch_bounds__(512) void k_prep(
    const float* __restrict__ cpb_w1, const float* __restrict__ cpb_b1,
    const float* __restrict__ cpb_w2, const float* __restrict__ qkv_w,
    const float* __restrict__ proj_w,
    float* __restrict__ biasfrag, f16* __restrict__ w_t, f16* __restrict__ p_t)
{
    __shared__ float cpb[225 * 8];
    int tid = threadIdx.x;
    if (blockIdx.x == 0) {
        if (tid < 225) {
            int a = tid / 15, b2 = tid % 15;
            float xa = (float)(a - 7) * (8.0f / 7.0f);
            float xb = (float)(b2 - 7) * (8.0f / 7.0f);
            float t0 = (xa < 0.f ? -1.f : 1.f) * log2f(1.0f + fabsf(xa)) * (1.0f / 3.0f);
            float t1 = (xb < 0.f ? -1.f : 1.f) * log2f(1.0f + fabsf(xb)) * (1.0f / 3.0f);
            float acc[8] = {0.f, 0.f, 0.f, 0.f, 0.f, 0.f, 0.f, 0.f};
            for (int j = 0; j < 512; ++j) {
                float hh = t0 * cpb_w1[j] + t1 * cpb_w1[512 + j] + cpb_b1[j];
                hh = fmaxf(hh, 0.0f);
                #pragma unroll
                for (int h = 0; h < 8; ++h) acc[h] += hh * cpb_w2[j * 8 + h];
            }
            #pragma unroll
            for (int h = 0; h < 8; ++h) cpb[tid * 8 + h] = acc[h];
        }
        __syncthreads();
        for (int f = tid; f < 32768; f += 512) {
            int r = f & 3, lane = (f >> 2) & 63, nt = (f >> 8) & 3, mt = (f >> 10) & 3, h = (f >> 12) & 7;
            int q = mt * 16 + ((lane >> 4) << 2) + r;
            int k = nt * 16 + (lane & 15);
            int idx = ((q >> 3) - (k >> 3) + 7) * 15 + ((q & 7) - (k & 7) + 7);
            float c = cpb[idx * 8 + h];
            biasfrag[f] = 16.0f / (1.0f + expf(-c));
        }
    } else {
        int base = (blockIdx.x - 1) * 512 + tid;
        const int stride = 128 * 512;
        for (int i = base; i < 768 * 256; i += stride) {
            int n = i >> 8, k = i & 255;
            w_t[i] = (f16)qkv_w[k * 768 + n];     // w_t[n][k] = W[k][n]
        }
        for (int i = base; i < 256 * 256; i += stride) {
            int n = i >> 8, k = i & 255;
            p_t[i] = (f16)proj_w[k * 256 + n];
        }
    }
}

// ---------------- fused main: block = window, wave = head.
// LDS: [0,32K) xt[64 pix][256 ch] f16 swizzled (reused as ot after barrier)
//      [32K,64K) 8 x 4K wave-private bounce
__global__ __launch_bounds__(512, 2) void k_fused(
    const float* __restrict__ x, const f16* __restrict__ w_t,
    const float* __restrict__ q_bias, const float* __restrict__ v_bias,
    const float* __restrict__ scale, const float* __restrict__ biasfrag,
    const f16* __restrict__ p_t, const float* __restrict__ proj_b,
    float* __restrict__ out)
{
    __shared__ char L[65536];
    const int tid = threadIdx.x;
    const int lane = tid & 63;
    const int h = tid >> 6;                   // wave = head
    const int l15 = lane & 15, g = lane >> 4;
    const int bw = blockIdx.x;
    const int win = bw & 1023, b = bw >> 10;
    const int wh = win >> 5, ww = win & 31;
    char* wb = L + 32768 + (h << 12);
    const f32x4 fz = {0.f, 0.f, 0.f, 0.f};
    const bool boundary = (wh == 31) || (ww == 31);

    // ---- phase 0: stage the window's 64 pixels (rolled coords), f32->f16
    {
        int pos = tid >> 3, tc = tid & 7;     // pos = (row<<3)|col in window
        int i2 = ((wh << 3) + (pos >> 3) + 4) & 255;
        int j2 = ((ww << 3) + (pos & 7) + 4) & 255;
        const float* xr = x + ((((long)b << 8) + i2) * 256 + j2) * 256;
        int swz = (pos & 7) << 4;
        #pragma unroll
        for (int rep = 0; rep < 4; ++rep) {
            int ch = rep * 64 + tc * 8;
            float4 v0 = *reinterpret_cast<const float4*>(xr + ch);
            float4 v1 = *reinterpret_cast<const float4*>(xr + ch + 4);
            f16x8 hv = { (f16)v0.x, (f16)v0.y, (f16)v0.z, (f16)v0.w,
                         (f16)v1.x, (f16)v1.y, (f16)v1.z, (f16)v1.w };
            *reinterpret_cast<f16x8*>(L + ((pos * 512 + ch * 2) ^ swz)) = hv;
        }
    }
    __syncthreads();   // barrier 1

    f16x8 qa[4], kb[4], vf[2][2];

    // ---- phase 1: qkv GEMM, wave h computes q/k/v columns [32h,32h+32)
    #pragma unroll 1
    for (int p = 0; p < 3; ++p) {
        f32x4 acc[4][2];
        #pragma unroll
        for (int mt = 0; mt < 4; ++mt) { acc[mt][0] = fz; acc[mt][1] = fz; }

        #pragma unroll
        for (int ks = 0; ks < 8; ++ks) {
            f16x8 a[4], bf2[2];
            #pragma unroll
            for (int mt = 0; mt < 4; ++mt) {
                int row = mt * 16 + l15;
                a[mt] = *reinterpret_cast<const f16x8*>(
                    L + ((row * 512 + ks * 64 + g * 16) ^ ((row & 7) << 4)));
            }
            #pragma unroll
            for (int nt = 0; nt < 2; ++nt)
                bf2[nt] = *reinterpret_cast<const f16x8*>(
                    w_t + ((p << 8) + (h << 5) + nt * 16 + l15) * 256 + ks * 32 + g * 8);
            #pragma unroll
            for (int mt = 0; mt < 4; ++mt)
                #pragma unroll
                for (int nt = 0; nt < 2; ++nt)
                    acc[mt][nt] = __builtin_amdgcn_mfma_f32_16x16x32_f16(a[mt], bf2[nt], acc[mt][nt], 0, 0, 0);
        }

        if (p < 2) {
            // q/k: (+bias), l2norm, (q: *logit_scale) -> bounce [pix][64B] -> frags
            float ls = 1.0f, b0 = 0.f, b1 = 0.f;
            if (p == 0) {
                ls = __expf(fminf(scale[h], LOG100));
                b0 = q_bias[(h << 5) + l15];
                b1 = q_bias[(h << 5) + 16 + l15];
            }
            #pragma unroll
            for (int mt = 0; mt < 4; ++mt)
                #pragma unroll
                for (int r = 0; r < 4; ++r) {
                    float a0 = acc[mt][0][r] + b0, a1 = acc[mt][1][r] + b1;
                    float s2 = a0 * a0 + a1 * a1;
                    s2 += __shfl_xor(s2, 1); s2 += __shfl_xor(s2, 2);
                    s2 += __shfl_xor(s2, 4); s2 += __shfl_xor(s2, 8);
                    float iv = ls / sqrtf(fmaxf(s2, EPS_L2));
                    int pos = mt * 16 + (g << 2) + r;
                    int sw = (pos & 7) << 4;
                    *reinterpret_cast<f16*>(wb + ((pos * 64 + l15 * 2) ^ sw)) = (f16)(a0 * iv);
                    *reinterpret_cast<f16*>(wb + ((pos * 64 + 32 + l15 * 2) ^ sw)) = (f16)(a1 * iv);
                }
            if (p == 0) {
                #pragma unroll
                for (int mt = 0; mt < 4; ++mt)
                    qa[mt] = *reinterpret_cast<const f16x8*>(
                        wb + (((mt * 16 + l15) * 64 + g * 16) ^ ((l15 & 7) << 4)));
            } else {
                #pragma unroll
                for (int mt = 0; mt < 4; ++mt)
                    kb[mt] = *reinterpret_cast<const f16x8*>(
                        wb + (((mt * 16 + l15) * 64 + g * 16) ^ ((l15 & 7) << 4)));
            }
        } else {
            // v: +bias -> bounce transposed [u 32][pix 64] (f16x4 over r) -> B-frags
            float b0 = v_bias[(h << 5) + l15], b1 = v_bias[(h << 5) + 16 + l15];
            #pragma unroll
            for (int mt = 0; mt < 4; ++mt)
                #pragma unroll
                for (int nt = 0; nt < 2; ++nt) {
                    float bsel = nt ? b1 : b0;
                    f16x4 pk = { (f16)(acc[mt][nt][0] + bsel), (f16)(acc[mt][nt][1] + bsel),
                                 (f16)(acc[mt][nt][2] + bsel), (f16)(acc[mt][nt][3] + bsel) };
                    int u = nt * 16 + l15;
                    int pix0 = mt * 16 + (g << 2);
                    *reinterpret_cast<f16x4*>(wb + ((u * 128 + pix0 * 2) ^ ((u & 7) << 4))) = pk;
                }
            #pragma unroll
            for (int nt = 0; nt < 2; ++nt)
                #pragma unroll
                for (int ks = 0; ks < 2; ++ks)
                    vf[nt][ks] = *reinterpret_cast<const f16x8*>(
                        wb + (((nt * 16 + l15) * 128 + ks * 64 + g * 16) ^ ((l15 & 7) << 4)));
        }
    }

    // ---- phase 2: S + bias (+mask), softmax (1/sum folded into P), pack
    f16x4 ph[4][4];
    #pragma unroll
    for (int mt = 0; mt < 4; ++mt) {
        f32x4 sr[4];
        #pragma unroll
        for (int nt = 0; nt < 4; ++nt)
            sr[nt] = __builtin_amdgcn_mfma_f32_16x16x32_f16(qa[mt], kb[nt], fz, 0, 0, 0);
        #pragma unroll
        for (int nt = 0; nt < 4; ++nt)
            sr[nt] += *reinterpret_cast<const f32x4*>(
                biasfrag + ((((h * 4 + mt) * 4 + nt) * 64 + lane) << 2));
        if (boundary) {
            #pragma unroll
            for (int r = 0; r < 4; ++r) {
                int q = mt * 16 + (g << 2) + r;
                int lq = seg2((wh << 3) + (q >> 3)) * 3 + seg2((ww << 3) + (q & 7));
                #pragma unroll
                for (int nt = 0; nt < 4; ++nt) {
                    int k = nt * 16 + l15;
                    int lk = seg2((wh << 3) + (k >> 3)) * 3 + seg2((ww << 3) + (k & 7));
                    if (lq != lk) sr[nt][r] -= 100.0f;
                }
            }
        }
        #pragma unroll
        for (int r = 0; r < 4; ++r) {
            float mx = fmaxf(fmaxf(sr[0][r], sr[1][r]), fmaxf(sr[2][r], sr[3][r]));
            mx = fmaxf(mx, __shfl_xor(mx, 1));
            mx = fmaxf(mx, __shfl_xor(mx, 2));
            mx = fmaxf(mx, __shfl_xor(mx, 4));
            mx = fmaxf(mx, __shfl_xor(mx, 8));
            float sm = 0.f;
            #pragma unroll
            for (int nt = 0; nt < 4; ++nt) {
                float e = __expf(sr[nt][r] - mx);
                sr[nt][r] = e;
                sm += e;
            }
            sm += __shfl_xor(sm, 1); sm += __shfl_xor(sm, 2);
            sm += __shfl_xor(sm, 4); sm += __shfl_xor(sm, 8);
            float inv = 1.0f / sm;
            #pragma unroll
            for (int nt = 0; nt < 4; ++nt) sr[nt][r] *= inv;
        }
        #pragma unroll
        for (int nt = 0; nt < 4; ++nt)
            ph[mt][nt] = f16x4{ (f16)sr[nt][0], (f16)sr[nt][1], (f16)sr[nt][2], (f16)sr[nt][3] };
    }

    // ---- PV in two 32-key halves via wave-private bounce (P already normalized)
    f32x4 o[4][2];
    #pragma unroll
    for (int mt = 0; mt < 4; ++mt) { o[mt][0] = fz; o[mt][1] = fz; }
    #pragma unroll
    for (int half = 0; half < 2; ++half) {
        #pragma unroll
        for (int mt = 0; mt < 4; ++mt)
            #pragma unroll
            for (int nt2 = 0; nt2 < 2; ++nt2)
                #pragma unroll
                for (int r = 0; r < 4; ++r) {
                    int q = mt * 16 + (g << 2) + r;
                    int key = nt2 * 16 + l15;
                    *reinterpret_cast<f16*>(wb + ((q * 64 + key * 2) ^ ((q & 3) << 4))) =
                        ph[mt][half * 2 + nt2][r];
                }
        #pragma unroll
        for (int mt = 0; mt < 4; ++mt) {
            int q = mt * 16 + l15;
            f16x8 pa = *reinterpret_cast<const f16x8*>(
                wb + ((q * 64 + g * 16) ^ ((q & 3) << 4)));
            #pragma unroll
            for (int nt = 0; nt < 2; ++nt)
                o[mt][nt] = __builtin_amdgcn_mfma_f32_16x16x32_f16(pa, vf[nt][half], o[mt][nt], 0, 0, 0);
        }
    }

    // ---- phase 3: O -> ot (reuse x-tile region), fused proj, direct store
    __syncthreads();   // barrier 2: all waves done reading x-tile
    #pragma unroll
    for (int mt = 0; mt < 4; ++mt)
        #pragma unroll
        for (int r = 0; r < 4; ++r) {
            int q = mt * 16 + (g << 2) + r;
            #pragma unroll
            for (int nt = 0; nt < 2; ++nt) {
                int ch = (h << 5) + nt * 16 + l15;
                *reinterpret_cast<f16*>(L + ((q * 512 + ch * 2) ^ ((q & 7) << 4))) =
                    (f16)o[mt][nt][r];
            }
        }
    __syncthreads();   // barrier 3

    const int c0 = h << 5;
    f32x4 pc[4][2];
    #pragma unroll
    for (int mt = 0; mt < 4; ++mt) { pc[mt][0] = fz; pc[mt][1] = fz; }
    #pragma unroll
    for (int ks = 0; ks < 8; ++ks) {
        f16x8 a[4], bfr[2];
        #pragma unroll
        for (int mt = 0; mt < 4; ++mt) {
            int q = mt * 16 + l15;
            a[mt] = *reinterpret_cast<const f16x8*>(
                L + ((q * 512 + ks * 64 + g * 16) ^ ((q & 7) << 4)));
        }
        #pragma unroll
        for (int nt = 0; nt < 2; ++nt)
            bfr[nt] = *reinterpret_cast<const f16x8*>(
                p_t + (c0 + nt * 16 + l15) * 256 + ks * 32 + g * 8);
        #pragma unroll
        for (int mt = 0; mt < 4; ++mt)
            #pragma unroll
            for (int nt = 0; nt < 2; ++nt)
                pc[mt][nt] = __builtin_amdgcn_mfma_f32_16x16x32_f16(a[mt], bfr[nt], pc[mt][nt], 0, 0, 0);
    }
    float pb0 = proj_b[c0 + l15], pb1 = proj_b[c0 + 16 + l15];
    #pragma unroll
    for (int mt = 0; mt < 4; ++mt)
        #pragma unroll
        for (int r = 0; r < 4; ++r) {
            int q = mt * 16 + (g << 2) + r;
            int i = ((wh << 3) + (q >> 3) + 4) & 255;   // roll(+4) un-partition
            int j = ((ww << 3) + (q & 7) + 4) & 255;
            long addr = (((long)b * 256 + i) * 256 + j) * 256;
            out[addr + c0 + l15]      = pc[mt][0][r] + pb0;
            out[addr + c0 + 16 + l15] = pc[mt][1][r] + pb1;
        }
}

extern "C" void kernel_launch(void* const* d_in, const int* in_sizes, int n_in,
                              void* d_out, int out_size, void* d_ws, size_t ws_size,
                              hipStream_t stream) {
    const float* x      = (const float*)d_in[0];
    const float* qkv_w  = (const float*)d_in[1];
    const float* q_bias = (const float*)d_in[2];
    const float* v_bias = (const float*)d_in[3];
    const float* scale  = (const float*)d_in[4];
    const float* cpb_w1 = (const float*)d_in[5];
    const float* cpb_b1 = (const float*)d_in[6];
    const float* cpb_w2 = (const float*)d_in[7];
    const float* proj_w = (const float*)d_in[8];
    const float* proj_b = (const float*)d_in[9];
    float* out = (float*)d_out;

    char* ws = (char*)d_ws;
    float* biasfrag = (float*)(ws);                         // 128 KiB
    f16* w_t  = (f16*)(ws + 131072);                        // 384 KiB
    f16* p_t  = (f16*)(ws + 524288);                        // 128 KiB

    hipLaunchKernelGGL(k_prep, dim3(129), dim3(512), 0, stream,
                       cpb_w1, cpb_b1, cpb_w2, qkv_w, proj_w, biasfrag, w_t, p_t);
    hipLaunchKernelGGL(k_fused, dim3(2048), dim3(512), 0, stream,
                       x, w_t, q_bias, v_bias, scale, biasfrag, p_t, proj_b, out);
}

// Round 9
// 349.424 us; speedup vs baseline: 1.6714x; 1.6714x over previous
//
#include <hip/hip_runtime.h>

// SwinV2 window attention — round 9: fused kernel, phase-1 UNROLLED into three
// explicit passes (unconditional qa/kb/vf assignment). Round 8's 671MB WRITE
// (vs 134 ideal) was scratch spill from the rolled loop + conditional
// persistent frags; this gives the allocator straight-line code.
// ws layout: [0,128K) biasfrag f32 | [128K,512K) w_t fp16[768][256]
//   | [512K,640K) p_t fp16[256][256]

typedef _Float16 f16;
typedef _Float16 f16x4 __attribute__((ext_vector_type(4)));
typedef _Float16 f16x8 __attribute__((ext_vector_type(8)));
typedef float f32x4 __attribute__((ext_vector_type(4)));

#define LOG100 4.6051701859880914f
#define EPS_L2 1.55e-5f

__device__ __forceinline__ int seg2(int p) { return (p >= 248) + (p >= 252); }

// ---------------- prep: CPB bias (MFMA C-frag order) + weight transpose/convert
__global__ __launch_bounds__(512) void k_prep(
    const float* __restrict__ cpb_w1, const float* __restrict__ cpb_b1,
    const float* __restrict__ cpb_w2, const float* __restrict__ qkv_w,
    const float* __restrict__ proj_w,
    float* __restrict__ biasfrag, f16* __restrict__ w_t, f16* __restrict__ p_t)
{
    __shared__ float cpb[225 * 8];
    int tid = threadIdx.x;
    if (blockIdx.x == 0) {
        if (tid < 225) {
            int a = tid / 15, b2 = tid % 15;
            float xa = (float)(a - 7) * (8.0f / 7.0f);
            float xb = (float)(b2 - 7) * (8.0f / 7.0f);
            float t0 = (xa < 0.f ? -1.f : 1.f) * log2f(1.0f + fabsf(xa)) * (1.0f / 3.0f);
            float t1 = (xb < 0.f ? -1.f : 1.f) * log2f(1.0f + fabsf(xb)) * (1.0f / 3.0f);
            float acc[8] = {0.f, 0.f, 0.f, 0.f, 0.f, 0.f, 0.f, 0.f};
            for (int j = 0; j < 512; ++j) {
                float hh = t0 * cpb_w1[j] + t1 * cpb_w1[512 + j] + cpb_b1[j];
                hh = fmaxf(hh, 0.0f);
                #pragma unroll
                for (int h = 0; h < 8; ++h) acc[h] += hh * cpb_w2[j * 8 + h];
            }
            #pragma unroll
            for (int h = 0; h < 8; ++h) cpb[tid * 8 + h] = acc[h];
        }
        __syncthreads();
        for (int f = tid; f < 32768; f += 512) {
            int r = f & 3, lane = (f >> 2) & 63, nt = (f >> 8) & 3, mt = (f >> 10) & 3, h = (f >> 12) & 7;
            int q = mt * 16 + ((lane >> 4) << 2) + r;
            int k = nt * 16 + (lane & 15);
            int idx = ((q >> 3) - (k >> 3) + 7) * 15 + ((q & 7) - (k & 7) + 7);
            float c = cpb[idx * 8 + h];
            biasfrag[f] = 16.0f / (1.0f + expf(-c));
        }
    } else {
        int base = (blockIdx.x - 1) * 512 + tid;
        const int stride = 128 * 512;
        for (int i = base; i < 768 * 256; i += stride) {
            int n = i >> 8, k = i & 255;
            w_t[i] = (f16)qkv_w[k * 768 + n];     // w_t[n][k] = W[k][n]
        }
        for (int i = base; i < 256 * 256; i += stride) {
            int n = i >> 8, k = i & 255;
            p_t[i] = (f16)proj_w[k * 256 + n];
        }
    }
}

// ---------------- fused main: block = window, wave = head.
// LDS: [0,32K) xt[64 pix][256 ch] f16 swizzled (reused as ot after barrier)
//      [32K,64K) 8 x 4K wave-private bounce
__global__ __launch_bounds__(512, 2) void k_fused(
    const float* __restrict__ x, const f16* __restrict__ w_t,
    const float* __restrict__ q_bias, const float* __restrict__ v_bias,
    const float* __restrict__ scale, const float* __restrict__ biasfrag,
    const f16* __restrict__ p_t, const float* __restrict__ proj_b,
    float* __restrict__ out)
{
    __shared__ char L[65536];
    const int tid = threadIdx.x;
    const int lane = tid & 63;
    const int h = tid >> 6;                   // wave = head
    const int l15 = lane & 15, g = lane >> 4;
    const int bw = blockIdx.x;
    const int win = bw & 1023, b = bw >> 10;
    const int wh = win >> 5, ww = win & 31;
    char* wb = L + 32768 + (h << 12);
    const f32x4 fz = {0.f, 0.f, 0.f, 0.f};
    const bool boundary = (wh == 31) || (ww == 31);

    // ---- phase 0: stage the window's 64 pixels (rolled coords), f32->f16
    {
        int pos = tid >> 3, tc = tid & 7;     // pos = (row<<3)|col in window
        int i2 = ((wh << 3) + (pos >> 3) + 4) & 255;
        int j2 = ((ww << 3) + (pos & 7) + 4) & 255;
        const float* xr = x + ((((long)b << 8) + i2) * 256 + j2) * 256;
        int swz = (pos & 7) << 4;
        #pragma unroll
        for (int rep = 0; rep < 4; ++rep) {
            int ch = rep * 64 + tc * 8;
            float4 v0 = *reinterpret_cast<const float4*>(xr + ch);
            float4 v1 = *reinterpret_cast<const float4*>(xr + ch + 4);
            f16x8 hv = { (f16)v0.x, (f16)v0.y, (f16)v0.z, (f16)v0.w,
                         (f16)v1.x, (f16)v1.y, (f16)v1.z, (f16)v1.w };
            *reinterpret_cast<f16x8*>(L + ((pos * 512 + ch * 2) ^ swz)) = hv;
        }
    }
    __syncthreads();   // barrier 1

    // GEMM pass over the staged x-tile: acc[mt][nt] += xt . w_t[strip p]
    auto gemm_pass = [&](int p, f32x4 acc[4][2]) {
        #pragma unroll
        for (int ks = 0; ks < 8; ++ks) {
            f16x8 a[4], bf2[2];
            #pragma unroll
            for (int mt = 0; mt < 4; ++mt) {
                int row = mt * 16 + l15;
                a[mt] = *reinterpret_cast<const f16x8*>(
                    L + ((row * 512 + ks * 64 + g * 16) ^ ((row & 7) << 4)));
            }
            #pragma unroll
            for (int nt = 0; nt < 2; ++nt)
                bf2[nt] = *reinterpret_cast<const f16x8*>(
                    w_t + ((p << 8) + (h << 5) + nt * 16 + l15) * 256 + ks * 32 + g * 8);
            #pragma unroll
            for (int mt = 0; mt < 4; ++mt)
                #pragma unroll
                for (int nt = 0; nt < 2; ++nt)
                    acc[mt][nt] = __builtin_amdgcn_mfma_f32_16x16x32_f16(a[mt], bf2[nt], acc[mt][nt], 0, 0, 0);
        }
    };

    // q/k epilogue: (+bias), l2norm, (*ls) -> wave bounce -> A/B frags
    auto norm_pass = [&](f32x4 acc[4][2], float ls, float b0, float b1, f16x8 frag[4]) {
        #pragma unroll
        for (int mt = 0; mt < 4; ++mt)
            #pragma unroll
            for (int r = 0; r < 4; ++r) {
                float a0 = acc[mt][0][r] + b0, a1 = acc[mt][1][r] + b1;
                float s2 = a0 * a0 + a1 * a1;
                s2 += __shfl_xor(s2, 1); s2 += __shfl_xor(s2, 2);
                s2 += __shfl_xor(s2, 4); s2 += __shfl_xor(s2, 8);
                float iv = ls / sqrtf(fmaxf(s2, EPS_L2));
                int pos = mt * 16 + (g << 2) + r;
                int sw = (pos & 7) << 4;
                *reinterpret_cast<f16*>(wb + ((pos * 64 + l15 * 2) ^ sw)) = (f16)(a0 * iv);
                *reinterpret_cast<f16*>(wb + ((pos * 64 + 32 + l15 * 2) ^ sw)) = (f16)(a1 * iv);
            }
        #pragma unroll
        for (int mt = 0; mt < 4; ++mt)
            frag[mt] = *reinterpret_cast<const f16x8*>(
                wb + (((mt * 16 + l15) * 64 + g * 16) ^ ((l15 & 7) << 4)));
    };

    f16x8 qa[4], kb[4], vf[2][2];

    // ---- pass q
    {
        f32x4 acc[4][2];
        #pragma unroll
        for (int mt = 0; mt < 4; ++mt) { acc[mt][0] = fz; acc[mt][1] = fz; }
        gemm_pass(0, acc);
        float ls = __expf(fminf(scale[h], LOG100));
        norm_pass(acc, ls, q_bias[(h << 5) + l15], q_bias[(h << 5) + 16 + l15], qa);
    }
    // ---- pass k
    {
        f32x4 acc[4][2];
        #pragma unroll
        for (int mt = 0; mt < 4; ++mt) { acc[mt][0] = fz; acc[mt][1] = fz; }
        gemm_pass(1, acc);
        norm_pass(acc, 1.0f, 0.f, 0.f, kb);
    }
    // ---- pass v
    {
        f32x4 acc[4][2];
        #pragma unroll
        for (int mt = 0; mt < 4; ++mt) { acc[mt][0] = fz; acc[mt][1] = fz; }
        gemm_pass(2, acc);
        float b0 = v_bias[(h << 5) + l15], b1 = v_bias[(h << 5) + 16 + l15];
        #pragma unroll
        for (int mt = 0; mt < 4; ++mt)
            #pragma unroll
            for (int nt = 0; nt < 2; ++nt) {
                float bsel = nt ? b1 : b0;
                f16x4 pk = { (f16)(acc[mt][nt][0] + bsel), (f16)(acc[mt][nt][1] + bsel),
                             (f16)(acc[mt][nt][2] + bsel), (f16)(acc[mt][nt][3] + bsel) };
                int u = nt * 16 + l15;
                int pix0 = mt * 16 + (g << 2);
                *reinterpret_cast<f16x4*>(wb + ((u * 128 + pix0 * 2) ^ ((u & 7) << 4))) = pk;
            }
        #pragma unroll
        for (int nt = 0; nt < 2; ++nt)
            #pragma unroll
            for (int ks = 0; ks < 2; ++ks)
                vf[nt][ks] = *reinterpret_cast<const f16x8*>(
                    wb + (((nt * 16 + l15) * 128 + ks * 64 + g * 16) ^ ((l15 & 7) << 4)));
    }

    // ---- phase 2: S + bias (+mask), softmax (1/sum folded into P), pack
    f16x4 ph[4][4];
    #pragma unroll
    for (int mt = 0; mt < 4; ++mt) {
        f32x4 sr[4];
        #pragma unroll
        for (int nt = 0; nt < 4; ++nt)
            sr[nt] = __builtin_amdgcn_mfma_f32_16x16x32_f16(qa[mt], kb[nt], fz, 0, 0, 0);
        #pragma unroll
        for (int nt = 0; nt < 4; ++nt)
            sr[nt] += *reinterpret_cast<const f32x4*>(
                biasfrag + ((((h * 4 + mt) * 4 + nt) * 64 + lane) << 2));
        if (boundary) {
            #pragma unroll
            for (int r = 0; r < 4; ++r) {
                int q = mt * 16 + (g << 2) + r;
                int lq = seg2((wh << 3) + (q >> 3)) * 3 + seg2((ww << 3) + (q & 7));
                #pragma unroll
                for (int nt = 0; nt < 4; ++nt) {
                    int k = nt * 16 + l15;
                    int lk = seg2((wh << 3) + (k >> 3)) * 3 + seg2((ww << 3) + (k & 7));
                    if (lq != lk) sr[nt][r] -= 100.0f;
                }
            }
        }
        #pragma unroll
        for (int r = 0; r < 4; ++r) {
            float mx = fmaxf(fmaxf(sr[0][r], sr[1][r]), fmaxf(sr[2][r], sr[3][r]));
            mx = fmaxf(mx, __shfl_xor(mx, 1));
            mx = fmaxf(mx, __shfl_xor(mx, 2));
            mx = fmaxf(mx, __shfl_xor(mx, 4));
            mx = fmaxf(mx, __shfl_xor(mx, 8));
            float sm = 0.f;
            #pragma unroll
            for (int nt = 0; nt < 4; ++nt) {
                float e = __expf(sr[nt][r] - mx);
                sr[nt][r] = e;
                sm += e;
            }
            sm += __shfl_xor(sm, 1); sm += __shfl_xor(sm, 2);
            sm += __shfl_xor(sm, 4); sm += __shfl_xor(sm, 8);
            float inv = 1.0f / sm;
            #pragma unroll
            for (int nt = 0; nt < 4; ++nt) sr[nt][r] *= inv;
        }
        #pragma unroll
        for (int nt = 0; nt < 4; ++nt)
            ph[mt][nt] = f16x4{ (f16)sr[nt][0], (f16)sr[nt][1], (f16)sr[nt][2], (f16)sr[nt][3] };
    }

    // ---- PV in two 32-key halves via wave-private bounce (P already normalized)
    f32x4 o[4][2];
    #pragma unroll
    for (int mt = 0; mt < 4; ++mt) { o[mt][0] = fz; o[mt][1] = fz; }
    #pragma unroll
    for (int half = 0; half < 2; ++half) {
        #pragma unroll
        for (int mt = 0; mt < 4; ++mt)
            #pragma unroll
            for (int nt2 = 0; nt2 < 2; ++nt2)
                #pragma unroll
                for (int r = 0; r < 4; ++r) {
                    int q = mt * 16 + (g << 2) + r;
                    int key = nt2 * 16 + l15;
                    *reinterpret_cast<f16*>(wb + ((q * 64 + key * 2) ^ ((q & 3) << 4))) =
                        ph[mt][half * 2 + nt2][r];
                }
        #pragma unroll
        for (int mt = 0; mt < 4; ++mt) {
            int q = mt * 16 + l15;
            f16x8 pa = *reinterpret_cast<const f16x8*>(
                wb + ((q * 64 + g * 16) ^ ((q & 3) << 4)));
            #pragma unroll
            for (int nt = 0; nt < 2; ++nt)
                o[mt][nt] = __builtin_amdgcn_mfma_f32_16x16x32_f16(pa, vf[nt][half], o[mt][nt], 0, 0, 0);
        }
    }

    // ---- phase 3: O -> ot (reuse x-tile region), fused proj, direct store
    __syncthreads();   // barrier 2: all waves done reading x-tile
    #pragma unroll
    for (int mt = 0; mt < 4; ++mt)
        #pragma unroll
        for (int r = 0; r < 4; ++r) {
            int q = mt * 16 + (g << 2) + r;
            #pragma unroll
            for (int nt = 0; nt < 2; ++nt) {
                int ch = (h << 5) + nt * 16 + l15;
                *reinterpret_cast<f16*>(L + ((q * 512 + ch * 2) ^ ((q & 7) << 4))) =
                    (f16)o[mt][nt][r];
            }
        }
    __syncthreads();   // barrier 3

    const int c0 = h << 5;
    f32x4 pc[4][2];
    #pragma unroll
    for (int mt = 0; mt < 4; ++mt) { pc[mt][0] = fz; pc[mt][1] = fz; }
    #pragma unroll
    for (int ks = 0; ks < 8; ++ks) {
        f16x8 a[4], bfr[2];
        #pragma unroll
        for (int mt = 0; mt < 4; ++mt) {
            int q = mt * 16 + l15;
            a[mt] = *reinterpret_cast<const f16x8*>(
                L + ((q * 512 + ks * 64 + g * 16) ^ ((q & 7) << 4)));
        }
        #pragma unroll
        for (int nt = 0; nt < 2; ++nt)
            bfr[nt] = *reinterpret_cast<const f16x8*>(
                p_t + (c0 + nt * 16 + l15) * 256 + ks * 32 + g * 8);
        #pragma unroll
        for (int mt = 0; mt < 4; ++mt)
            #pragma unroll
            for (int nt = 0; nt < 2; ++nt)
                pc[mt][nt] = __builtin_amdgcn_mfma_f32_16x16x32_f16(a[mt], bfr[nt], pc[mt][nt], 0, 0, 0);
    }
    float pb0 = proj_b[c0 + l15], pb1 = proj_b[c0 + 16 + l15];
    #pragma unroll
    for (int mt = 0; mt < 4; ++mt)
        #pragma unroll
        for (int r = 0; r < 4; ++r) {
            int q = mt * 16 + (g << 2) + r;
            int i = ((wh << 3) + (q >> 3) + 4) & 255;   // roll(+4) un-partition
            int j = ((ww << 3) + (q & 7) + 4) & 255;
            long addr = (((long)b * 256 + i) * 256 + j) * 256;
            out[addr + c0 + l15]      = pc[mt][0][r] + pb0;
            out[addr + c0 + 16 + l15] = pc[mt][1][r] + pb1;
        }
}

extern "C" void kernel_launch(void* const* d_in, const int* in_sizes, int n_in,
                              void* d_out, int out_size, void* d_ws, size_t ws_size,
                              hipStream_t stream) {
    const float* x      = (const float*)d_in[0];
    const float* qkv_w  = (const float*)d_in[1];
    const float* q_bias = (const float*)d_in[2];
    const float* v_bias = (const float*)d_in[3];
    const float* scale  = (const float*)d_in[4];
    const float* cpb_w1 = (const float*)d_in[5];
    const float* cpb_b1 = (const float*)d_in[6];
    const float* cpb_w2 = (const float*)d_in[7];
    const float* proj_w = (const float*)d_in[8];
    const float* proj_b = (const float*)d_in[9];
    float* out = (float*)d_out;

    char* ws = (char*)d_ws;
    float* biasfrag = (float*)(ws);                         // 128 KiB
    f16* w_t  = (f16*)(ws + 131072);                        // 384 KiB
    f16* p_t  = (f16*)(ws + 524288);                        // 128 KiB

    hipLaunchKernelGGL(k_prep, dim3(129), dim3(512), 0, stream,
                       cpb_w1, cpb_b1, cpb_w2, qkv_w, proj_w, biasfrag, w_t, p_t);
    hipLaunchKernelGGL(k_fused, dim3(2048), dim3(512), 0, stream,
                       x, w_t, q_bias, v_bias, scale, biasfrag, p_t, proj_b, out);
}

// Round 10
// 341.967 us; speedup vs baseline: 1.7078x; 1.0218x over previous
//
#include <hip/hip_runtime.h>

// SwinV2 window attention — round 10: (a) k_prep CPB MLP parallelized+LDS-staged
// (was ~30us of serial global-latency on one block), (b) k_fused q+k GEMM passes
// merged into one acc[4][4] pass (shared A-frags, 2x MFMA ILP, 4 B-loads/ks).
// ws layout: [0,128K) biasfrag f32 | [128K,512K) w_t fp16[768][256]
//   | [512K,640K) p_t fp16[256][256]

typedef _Float16 f16;
typedef _Float16 f16x4 __attribute__((ext_vector_type(4)));
typedef _Float16 f16x8 __attribute__((ext_vector_type(8)));
typedef float f32x4 __attribute__((ext_vector_type(4)));

#define LOG100 4.6051701859880914f
#define EPS_L2 1.55e-5f

__device__ __forceinline__ int seg2(int p) { return (p >= 248) + (p >= 252); }

// ---------------- prep: CPB bias (MFMA C-frag order) + weight transpose/convert
__global__ __launch_bounds__(512) void k_prep(
    const float* __restrict__ cpb_w1, const float* __restrict__ cpb_b1,
    const float* __restrict__ cpb_w2, const float* __restrict__ qkv_w,
    const float* __restrict__ proj_w,
    float* __restrict__ biasfrag, f16* __restrict__ w_t, f16* __restrict__ p_t)
{
    int tid = threadIdx.x;
    if (blockIdx.x == 0) {
        __shared__ float Lw1[1024];
        __shared__ float Lb1[512];
        __shared__ float Lw2[4096];
        __shared__ float part[450 * 8];
        __shared__ float cpb[225 * 8];
        // stage MLP weights to LDS (coalesced)
        #pragma unroll
        for (int i = tid; i < 1024; i += 512) Lw1[i] = cpb_w1[i];
        if (tid < 512) Lb1[tid] = cpb_b1[tid];
        #pragma unroll
        for (int i = tid; i < 4096; i += 512) Lw2[i] = cpb_w2[i];
        __syncthreads();
        // 450 threads: (entry e, j-half), 256 js each, all LDS-served
        {
            int e = tid >> 1, half = tid & 1;
            if (e < 225) {
                int a = e / 15, b2 = e % 15;
                float xa = (float)(a - 7) * (8.0f / 7.0f);
                float xb = (float)(b2 - 7) * (8.0f / 7.0f);
                float t0 = (xa < 0.f ? -1.f : 1.f) * log2f(1.0f + fabsf(xa)) * (1.0f / 3.0f);
                float t1 = (xb < 0.f ? -1.f : 1.f) * log2f(1.0f + fabsf(xb)) * (1.0f / 3.0f);
                float acc[8] = {0.f, 0.f, 0.f, 0.f, 0.f, 0.f, 0.f, 0.f};
                int j0 = half << 8;
                #pragma unroll 4
                for (int j = j0; j < j0 + 256; ++j) {
                    float hh = fmaxf(t0 * Lw1[j] + t1 * Lw1[512 + j] + Lb1[j], 0.0f);
                    #pragma unroll
                    for (int h = 0; h < 8; ++h) acc[h] += hh * Lw2[j * 8 + h];
                }
                #pragma unroll
                for (int h = 0; h < 8; ++h) part[tid * 8 + h] = acc[h];
            }
        }
        __syncthreads();
        if (tid < 225) {
            #pragma unroll
            for (int h = 0; h < 8; ++h)
                cpb[tid * 8 + h] = part[tid * 16 + h] + part[tid * 16 + 8 + h];
        }
        __syncthreads();
        // biasfrag flat index f = (((h*4+mt)*4+nt)*64+lane)*4 + r
        for (int f = tid; f < 32768; f += 512) {
            int r = f & 3, lane = (f >> 2) & 63, nt = (f >> 8) & 3, mt = (f >> 10) & 3, h = (f >> 12) & 7;
            int q = mt * 16 + ((lane >> 4) << 2) + r;
            int k = nt * 16 + (lane & 15);
            int idx = ((q >> 3) - (k >> 3) + 7) * 15 + ((q & 7) - (k & 7) + 7);
            float c = cpb[idx * 8 + h];
            biasfrag[f] = 16.0f / (1.0f + expf(-c));
        }
    } else {
        int base = (blockIdx.x - 1) * 512 + tid;
        const int stride = 128 * 512;
        for (int i = base; i < 768 * 256; i += stride) {
            int n = i >> 8, k = i & 255;
            w_t[i] = (f16)qkv_w[k * 768 + n];     // w_t[n][k] = W[k][n]
        }
        for (int i = base; i < 256 * 256; i += stride) {
            int n = i >> 8, k = i & 255;
            p_t[i] = (f16)proj_w[k * 256 + n];
        }
    }
}

// ---------------- fused main: block = window, wave = head.
// LDS: [0,32K) xt[64 pix][256 ch] f16 swizzled (reused as ot after barrier)
//      [32K,64K) 8 x 4K wave-private bounce
__global__ __launch_bounds__(512, 2) void k_fused(
    const float* __restrict__ x, const f16* __restrict__ w_t,
    const float* __restrict__ q_bias, const float* __restrict__ v_bias,
    const float* __restrict__ scale, const float* __restrict__ biasfrag,
    const f16* __restrict__ p_t, const float* __restrict__ proj_b,
    float* __restrict__ out)
{
    __shared__ char L[65536];
    const int tid = threadIdx.x;
    const int lane = tid & 63;
    const int h = tid >> 6;                   // wave = head
    const int l15 = lane & 15, g = lane >> 4;
    const int bw = blockIdx.x;
    const int win = bw & 1023, b = bw >> 10;
    const int wh = win >> 5, ww = win & 31;
    char* wb = L + 32768 + (h << 12);
    const f32x4 fz = {0.f, 0.f, 0.f, 0.f};
    const bool boundary = (wh == 31) || (ww == 31);

    // ---- phase 0: stage the window's 64 pixels (rolled coords), f32->f16
    {
        int pos = tid >> 3, tc = tid & 7;     // pos = (row<<3)|col in window
        int i2 = ((wh << 3) + (pos >> 3) + 4) & 255;
        int j2 = ((ww << 3) + (pos & 7) + 4) & 255;
        const float* xr = x + ((((long)b << 8) + i2) * 256 + j2) * 256;
        int swz = (pos & 7) << 4;
        #pragma unroll
        for (int rep = 0; rep < 4; ++rep) {
            int ch = rep * 64 + tc * 8;
            float4 v0 = *reinterpret_cast<const float4*>(xr + ch);
            float4 v1 = *reinterpret_cast<const float4*>(xr + ch + 4);
            f16x8 hv = { (f16)v0.x, (f16)v0.y, (f16)v0.z, (f16)v0.w,
                         (f16)v1.x, (f16)v1.y, (f16)v1.z, (f16)v1.w };
            *reinterpret_cast<f16x8*>(L + ((pos * 512 + ch * 2) ^ swz)) = hv;
        }
    }
    __syncthreads();   // barrier 1

    f16x8 qa[4], kb[4], vf[2][2];

    // q/k epilogue: (+bias), l2norm, (*ls) -> wave bounce -> A/B frags
    auto norm_pass = [&](f32x4 a0c[4], f32x4 a1c[4], float ls, float b0, float b1, f16x8 frag[4]) {
        #pragma unroll
        for (int mt = 0; mt < 4; ++mt)
            #pragma unroll
            for (int r = 0; r < 4; ++r) {
                float a0 = a0c[mt][r] + b0, a1 = a1c[mt][r] + b1;
                float s2 = a0 * a0 + a1 * a1;
                s2 += __shfl_xor(s2, 1); s2 += __shfl_xor(s2, 2);
                s2 += __shfl_xor(s2, 4); s2 += __shfl_xor(s2, 8);
                float iv = ls / sqrtf(fmaxf(s2, EPS_L2));
                int pos = mt * 16 + (g << 2) + r;
                int sw = (pos & 7) << 4;
                *reinterpret_cast<f16*>(wb + ((pos * 64 + l15 * 2) ^ sw)) = (f16)(a0 * iv);
                *reinterpret_cast<f16*>(wb + ((pos * 64 + 32 + l15 * 2) ^ sw)) = (f16)(a1 * iv);
            }
        #pragma unroll
        for (int mt = 0; mt < 4; ++mt)
            frag[mt] = *reinterpret_cast<const f16x8*>(
                wb + (((mt * 16 + l15) * 64 + g * 16) ^ ((l15 & 7) << 4)));
    };

    // ---- merged q+k GEMM pass: acc[mt][0,1]=q cols, acc[mt][2,3]=k cols
    {
        f32x4 acc[4][4];
        #pragma unroll
        for (int mt = 0; mt < 4; ++mt)
            #pragma unroll
            for (int n4 = 0; n4 < 4; ++n4) acc[mt][n4] = fz;

        #pragma unroll
        for (int ks = 0; ks < 8; ++ks) {
            f16x8 a[4], bb4[4];
            #pragma unroll
            for (int mt = 0; mt < 4; ++mt) {
                int row = mt * 16 + l15;
                a[mt] = *reinterpret_cast<const f16x8*>(
                    L + ((row * 512 + ks * 64 + g * 16) ^ ((row & 7) << 4)));
            }
            #pragma unroll
            for (int nt = 0; nt < 2; ++nt) {
                bb4[nt] = *reinterpret_cast<const f16x8*>(
                    w_t + ((h << 5) + nt * 16 + l15) * 256 + ks * 32 + g * 8);
                bb4[2 + nt] = *reinterpret_cast<const f16x8*>(
                    w_t + (256 + (h << 5) + nt * 16 + l15) * 256 + ks * 32 + g * 8);
            }
            #pragma unroll
            for (int mt = 0; mt < 4; ++mt)
                #pragma unroll
                for (int n4 = 0; n4 < 4; ++n4)
                    acc[mt][n4] = __builtin_amdgcn_mfma_f32_16x16x32_f16(a[mt], bb4[n4], acc[mt][n4], 0, 0, 0);
        }

        f32x4 aq0[4], aq1[4], ak0[4], ak1[4];
        #pragma unroll
        for (int mt = 0; mt < 4; ++mt) {
            aq0[mt] = acc[mt][0]; aq1[mt] = acc[mt][1];
            ak0[mt] = acc[mt][2]; ak1[mt] = acc[mt][3];
        }
        float ls = __expf(fminf(scale[h], LOG100));
        norm_pass(aq0, aq1, ls, q_bias[(h << 5) + l15], q_bias[(h << 5) + 16 + l15], qa);
        norm_pass(ak0, ak1, 1.0f, 0.f, 0.f, kb);
    }

    // ---- pass v
    {
        f32x4 acc[4][2];
        #pragma unroll
        for (int mt = 0; mt < 4; ++mt) { acc[mt][0] = fz; acc[mt][1] = fz; }
        #pragma unroll
        for (int ks = 0; ks < 8; ++ks) {
            f16x8 a[4], bf2[2];
            #pragma unroll
            for (int mt = 0; mt < 4; ++mt) {
                int row = mt * 16 + l15;
                a[mt] = *reinterpret_cast<const f16x8*>(
                    L + ((row * 512 + ks * 64 + g * 16) ^ ((row & 7) << 4)));
            }
            #pragma unroll
            for (int nt = 0; nt < 2; ++nt)
                bf2[nt] = *reinterpret_cast<const f16x8*>(
                    w_t + (512 + (h << 5) + nt * 16 + l15) * 256 + ks * 32 + g * 8);
            #pragma unroll
            for (int mt = 0; mt < 4; ++mt)
                #pragma unroll
                for (int nt = 0; nt < 2; ++nt)
                    acc[mt][nt] = __builtin_amdgcn_mfma_f32_16x16x32_f16(a[mt], bf2[nt], acc[mt][nt], 0, 0, 0);
        }
        float b0 = v_bias[(h << 5) + l15], b1 = v_bias[(h << 5) + 16 + l15];
        #pragma unroll
        for (int mt = 0; mt < 4; ++mt)
            #pragma unroll
            for (int nt = 0; nt < 2; ++nt) {
                float bsel = nt ? b1 : b0;
                f16x4 pk = { (f16)(acc[mt][nt][0] + bsel), (f16)(acc[mt][nt][1] + bsel),
                             (f16)(acc[mt][nt][2] + bsel), (f16)(acc[mt][nt][3] + bsel) };
                int u = nt * 16 + l15;
                int pix0 = mt * 16 + (g << 2);
                *reinterpret_cast<f16x4*>(wb + ((u * 128 + pix0 * 2) ^ ((u & 7) << 4))) = pk;
            }
        #pragma unroll
        for (int nt = 0; nt < 2; ++nt)
            #pragma unroll
            for (int ks = 0; ks < 2; ++ks)
                vf[nt][ks] = *reinterpret_cast<const f16x8*>(
                    wb + (((nt * 16 + l15) * 128 + ks * 64 + g * 16) ^ ((l15 & 7) << 4)));
    }

    // ---- phase 2: S + bias (+mask), softmax (1/sum folded into P), pack
    f16x4 ph[4][4];
    #pragma unroll
    for (int mt = 0; mt < 4; ++mt) {
        f32x4 sr[4];
        #pragma unroll
        for (int nt = 0; nt < 4; ++nt)
            sr[nt] = __builtin_amdgcn_mfma_f32_16x16x32_f16(qa[mt], kb[nt], fz, 0, 0, 0);
        #pragma unroll
        for (int nt = 0; nt < 4; ++nt)
            sr[nt] += *reinterpret_cast<const f32x4*>(
                biasfrag + ((((h * 4 + mt) * 4 + nt) * 64 + lane) << 2));
        if (boundary) {
            #pragma unroll
            for (int r = 0; r < 4; ++r) {
                int q = mt * 16 + (g << 2) + r;
                int lq = seg2((wh << 3) + (q >> 3)) * 3 + seg2((ww << 3) + (q & 7));
                #pragma unroll
                for (int nt = 0; nt < 4; ++nt) {
                    int k = nt * 16 + l15;
                    int lk = seg2((wh << 3) + (k >> 3)) * 3 + seg2((ww << 3) + (k & 7));
                    if (lq != lk) sr[nt][r] -= 100.0f;
                }
            }
        }
        #pragma unroll
        for (int r = 0; r < 4; ++r) {
            float mx = fmaxf(fmaxf(sr[0][r], sr[1][r]), fmaxf(sr[2][r], sr[3][r]));
            mx = fmaxf(mx, __shfl_xor(mx, 1));
            mx = fmaxf(mx, __shfl_xor(mx, 2));
            mx = fmaxf(mx, __shfl_xor(mx, 4));
            mx = fmaxf(mx, __shfl_xor(mx, 8));
            float sm = 0.f;
            #pragma unroll
            for (int nt = 0; nt < 4; ++nt) {
                float e = __expf(sr[nt][r] - mx);
                sr[nt][r] = e;
                sm += e;
            }
            sm += __shfl_xor(sm, 1); sm += __shfl_xor(sm, 2);
            sm += __shfl_xor(sm, 4); sm += __shfl_xor(sm, 8);
            float inv = 1.0f / sm;
            #pragma unroll
            for (int nt = 0; nt < 4; ++nt) sr[nt][r] *= inv;
        }
        #pragma unroll
        for (int nt = 0; nt < 4; ++nt)
            ph[mt][nt] = f16x4{ (f16)sr[nt][0], (f16)sr[nt][1], (f16)sr[nt][2], (f16)sr[nt][3] };
    }

    // ---- PV in two 32-key halves via wave-private bounce (P already normalized)
    f32x4 o[4][2];
    #pragma unroll
    for (int mt = 0; mt < 4; ++mt) { o[mt][0] = fz; o[mt][1] = fz; }
    #pragma unroll
    for (int half = 0; half < 2; ++half) {
        #pragma unroll
        for (int mt = 0; mt < 4; ++mt)
            #pragma unroll
            for (int nt2 = 0; nt2 < 2; ++nt2)
                #pragma unroll
                for (int r = 0; r < 4; ++r) {
                    int q = mt * 16 + (g << 2) + r;
                    int key = nt2 * 16 + l15;
                    *reinterpret_cast<f16*>(wb + ((q * 64 + key * 2) ^ ((q & 3) << 4))) =
                        ph[mt][half * 2 + nt2][r];
                }
        #pragma unroll
        for (int mt = 0; mt < 4; ++mt) {
            int q = mt * 16 + l15;
            f16x8 pa = *reinterpret_cast<const f16x8*>(
                wb + ((q * 64 + g * 16) ^ ((q & 3) << 4)));
            #pragma unroll
            for (int nt = 0; nt < 2; ++nt)
                o[mt][nt] = __builtin_amdgcn_mfma_f32_16x16x32_f16(pa, vf[nt][half], o[mt][nt], 0, 0, 0);
        }
    }

    // ---- phase 3: O -> ot (reuse x-tile region), fused proj, direct store
    __syncthreads();   // barrier 2: all waves done reading x-tile
    #pragma unroll
    for (int mt = 0; mt < 4; ++mt)
        #pragma unroll
        for (int r = 0; r < 4; ++r) {
            int q = mt * 16 + (g << 2) + r;
            #pragma unroll
            for (int nt = 0; nt < 2; ++nt) {
                int ch = (h << 5) + nt * 16 + l15;
                *reinterpret_cast<f16*>(L + ((q * 512 + ch * 2) ^ ((q & 7) << 4))) =
                    (f16)o[mt][nt][r];
            }
        }
    __syncthreads();   // barrier 3

    const int c0 = h << 5;
    f32x4 pc[4][2];
    #pragma unroll
    for (int mt = 0; mt < 4; ++mt) { pc[mt][0] = fz; pc[mt][1] = fz; }
    #pragma unroll
    for (int ks = 0; ks < 8; ++ks) {
        f16x8 a[4], bfr[2];
        #pragma unroll
        for (int mt = 0; mt < 4; ++mt) {
            int q = mt * 16 + l15;
            a[mt] = *reinterpret_cast<const f16x8*>(
                L + ((q * 512 + ks * 64 + g * 16) ^ ((q & 7) << 4)));
        }
        #pragma unroll
        for (int nt = 0; nt < 2; ++nt)
            bfr[nt] = *reinterpret_cast<const f16x8*>(
                p_t + (c0 + nt * 16 + l15) * 256 + ks * 32 + g * 8);
        #pragma unroll
        for (int mt = 0; mt < 4; ++mt)
            #pragma unroll
            for (int nt = 0; nt < 2; ++nt)
                pc[mt][nt] = __builtin_amdgcn_mfma_f32_16x16x32_f16(a[mt], bfr[nt], pc[mt][nt], 0, 0, 0);
    }
    float pb0 = proj_b[c0 + l15], pb1 = proj_b[c0 + 16 + l15];
    #pragma unroll
    for (int mt = 0; mt < 4; ++mt)
        #pragma unroll
        for (int r = 0; r < 4; ++r) {
            int q = mt * 16 + (g << 2) + r;
            int i = ((wh << 3) + (q >> 3) + 4) & 255;   // roll(+4) un-partition
            int j = ((ww << 3) + (q & 7) + 4) & 255;
            long addr = (((long)b * 256 + i) * 256 + j) * 256;
            out[addr + c0 + l15]      = pc[mt][0][r] + pb0;
            out[addr + c0 + 16 + l15] = pc[mt][1][r] + pb1;
        }
}

extern "C" void kernel_launch(void* const* d_in, const int* in_sizes, int n_in,
                              void* d_out, int out_size, void* d_ws, size_t ws_size,
                              hipStream_t stream) {
    const float* x      = (const float*)d_in[0];
    const float* qkv_w  = (const float*)d_in[1];
    const float* q_bias = (const float*)d_in[2];
    const float* v_bias = (const float*)d_in[3];
    const float* scale  = (const float*)d_in[4];
    const float* cpb_w1 = (const float*)d_in[5];
    const float* cpb_b1 = (const float*)d_in[6];
    const float* cpb_w2 = (const float*)d_in[7];
    const float* proj_w = (const float*)d_in[8];
    const float* proj_b = (const float*)d_in[9];
    float* out = (float*)d_out;

    char* ws = (char*)d_ws;
    float* biasfrag = (float*)(ws);                         // 128 KiB
    f16* w_t  = (f16*)(ws + 131072);                        // 384 KiB
    f16* p_t  = (f16*)(ws + 524288);                        // 128 KiB

    hipLaunchKernelGGL(k_prep, dim3(129), dim3(512), 0, stream,
                       cpb_w1, cpb_b1, cpb_w2, qkv_w, proj_w, biasfrag, w_t, p_t);
    hipLaunchKernelGGL(k_fused, dim3(2048), dim3(512), 0, stream,
                       x, w_t, q_bias, v_bias, scale, biasfrag, p_t, proj_b, out);
}

// Round 11
// 293.321 us; speedup vs baseline: 1.9910x; 1.1658x over previous
//
#include <hip/hip_runtime.h>

// SwinV2 window attention — round 11: k_fused with NO vgpr cap (launch_bounds(512))
// and q/k/v GEMM merged into ONE pass (acc[4][6], shared A-frags, 24-way MFMA ILP).
// Rationale: occupancy is pinned at 1 block/CU by VGPR+AGPR total (unified file)
// for any VGPR in (128,256] — so the (512,2) cap only caused spills (R10: 241MB
// writes vs 131 ideal), never bought occupancy.
// ws layout: [0,128K) biasfrag f32 | [128K,512K) w_t fp16[768][256]
//   | [512K,640K) p_t fp16[256][256]

typedef _Float16 f16;
typedef _Float16 f16x4 __attribute__((ext_vector_type(4)));
typedef _Float16 f16x8 __attribute__((ext_vector_type(8)));
typedef float f32x4 __attribute__((ext_vector_type(4)));

#define LOG100 4.6051701859880914f
#define EPS_L2 1.55e-5f

__device__ __forceinline__ int seg2(int p) { return (p >= 248) + (p >= 252); }

// ---------------- prep: CPB bias (MFMA C-frag order) + weight transpose/convert
__global__ __launch_bounds__(512) void k_prep(
    const float* __restrict__ cpb_w1, const float* __restrict__ cpb_b1,
    const float* __restrict__ cpb_w2, const float* __restrict__ qkv_w,
    const float* __restrict__ proj_w,
    float* __restrict__ biasfrag, f16* __restrict__ w_t, f16* __restrict__ p_t)
{
    int tid = threadIdx.x;
    if (blockIdx.x == 0) {
        __shared__ float Lw1[1024];
        __shared__ float Lb1[512];
        __shared__ float Lw2[4096];
        __shared__ float part[450 * 8];
        __shared__ float cpb[225 * 8];
        #pragma unroll
        for (int i = tid; i < 1024; i += 512) Lw1[i] = cpb_w1[i];
        if (tid < 512) Lb1[tid] = cpb_b1[tid];
        #pragma unroll
        for (int i = tid; i < 4096; i += 512) Lw2[i] = cpb_w2[i];
        __syncthreads();
        {
            int e = tid >> 1, half = tid & 1;
            if (e < 225) {
                int a = e / 15, b2 = e % 15;
                float xa = (float)(a - 7) * (8.0f / 7.0f);
                float xb = (float)(b2 - 7) * (8.0f / 7.0f);
                float t0 = (xa < 0.f ? -1.f : 1.f) * log2f(1.0f + fabsf(xa)) * (1.0f / 3.0f);
                float t1 = (xb < 0.f ? -1.f : 1.f) * log2f(1.0f + fabsf(xb)) * (1.0f / 3.0f);
                float acc[8] = {0.f, 0.f, 0.f, 0.f, 0.f, 0.f, 0.f, 0.f};
                int j0 = half << 8;
                #pragma unroll 4
                for (int j = j0; j < j0 + 256; ++j) {
                    float hh = fmaxf(t0 * Lw1[j] + t1 * Lw1[512 + j] + Lb1[j], 0.0f);
                    #pragma unroll
                    for (int h = 0; h < 8; ++h) acc[h] += hh * Lw2[j * 8 + h];
                }
                #pragma unroll
                for (int h = 0; h < 8; ++h) part[tid * 8 + h] = acc[h];
            }
        }
        __syncthreads();
        if (tid < 225) {
            #pragma unroll
            for (int h = 0; h < 8; ++h)
                cpb[tid * 8 + h] = part[tid * 16 + h] + part[tid * 16 + 8 + h];
        }
        __syncthreads();
        for (int f = tid; f < 32768; f += 512) {
            int r = f & 3, lane = (f >> 2) & 63, nt = (f >> 8) & 3, mt = (f >> 10) & 3, h = (f >> 12) & 7;
            int q = mt * 16 + ((lane >> 4) << 2) + r;
            int k = nt * 16 + (lane & 15);
            int idx = ((q >> 3) - (k >> 3) + 7) * 15 + ((q & 7) - (k & 7) + 7);
            float c = cpb[idx * 8 + h];
            biasfrag[f] = 16.0f / (1.0f + expf(-c));
        }
    } else {
        int base = (blockIdx.x - 1) * 512 + tid;
        const int stride = 128 * 512;
        for (int i = base; i < 768 * 256; i += stride) {
            int n = i >> 8, k = i & 255;
            w_t[i] = (f16)qkv_w[k * 768 + n];     // w_t[n][k] = W[k][n]
        }
        for (int i = base; i < 256 * 256; i += stride) {
            int n = i >> 8, k = i & 255;
            p_t[i] = (f16)proj_w[k * 256 + n];
        }
    }
}

// ---------------- fused main: block = window, wave = head.
// LDS: [0,32K) xt[64 pix][256 ch] f16 swizzled (reused as ot after barrier)
//      [32K,64K) 8 x 4K wave-private bounce
__global__ __launch_bounds__(512) void k_fused(
    const float* __restrict__ x, const f16* __restrict__ w_t,
    const float* __restrict__ q_bias, const float* __restrict__ v_bias,
    const float* __restrict__ scale, const float* __restrict__ biasfrag,
    const f16* __restrict__ p_t, const float* __restrict__ proj_b,
    float* __restrict__ out)
{
    __shared__ char L[65536];
    const int tid = threadIdx.x;
    const int lane = tid & 63;
    const int h = tid >> 6;                   // wave = head
    const int l15 = lane & 15, g = lane >> 4;
    const int bw = blockIdx.x;
    const int win = bw & 1023, b = bw >> 10;
    const int wh = win >> 5, ww = win & 31;
    char* wb = L + 32768 + (h << 12);
    const f32x4 fz = {0.f, 0.f, 0.f, 0.f};
    const bool boundary = (wh == 31) || (ww == 31);

    // ---- phase 0: stage the window's 64 pixels (rolled coords), f32->f16
    {
        int pos = tid >> 3, tc = tid & 7;     // pos = (row<<3)|col in window
        int i2 = ((wh << 3) + (pos >> 3) + 4) & 255;
        int j2 = ((ww << 3) + (pos & 7) + 4) & 255;
        const float* xr = x + ((((long)b << 8) + i2) * 256 + j2) * 256;
        int swz = (pos & 7) << 4;
        #pragma unroll
        for (int rep = 0; rep < 4; ++rep) {
            int ch = rep * 64 + tc * 8;
            float4 v0 = *reinterpret_cast<const float4*>(xr + ch);
            float4 v1 = *reinterpret_cast<const float4*>(xr + ch + 4);
            f16x8 hv = { (f16)v0.x, (f16)v0.y, (f16)v0.z, (f16)v0.w,
                         (f16)v1.x, (f16)v1.y, (f16)v1.z, (f16)v1.w };
            *reinterpret_cast<f16x8*>(L + ((pos * 512 + ch * 2) ^ swz)) = hv;
        }
    }
    __syncthreads();   // barrier 1

    f16x8 qa[4], kb[4], vf[2][2];

    // q/k epilogue: (+bias), l2norm, (*ls) -> wave bounce -> A/B frags
    auto norm_pass = [&](f32x4 a0c[4], f32x4 a1c[4], float ls, float b0, float b1, f16x8 frag[4]) {
        #pragma unroll
        for (int mt = 0; mt < 4; ++mt)
            #pragma unroll
            for (int r = 0; r < 4; ++r) {
                float a0 = a0c[mt][r] + b0, a1 = a1c[mt][r] + b1;
                float s2 = a0 * a0 + a1 * a1;
                s2 += __shfl_xor(s2, 1); s2 += __shfl_xor(s2, 2);
                s2 += __shfl_xor(s2, 4); s2 += __shfl_xor(s2, 8);
                float iv = ls / sqrtf(fmaxf(s2, EPS_L2));
                int pos = mt * 16 + (g << 2) + r;
                int sw = (pos & 7) << 4;
                *reinterpret_cast<f16*>(wb + ((pos * 64 + l15 * 2) ^ sw)) = (f16)(a0 * iv);
                *reinterpret_cast<f16*>(wb + ((pos * 64 + 32 + l15 * 2) ^ sw)) = (f16)(a1 * iv);
            }
        #pragma unroll
        for (int mt = 0; mt < 4; ++mt)
            frag[mt] = *reinterpret_cast<const f16x8*>(
                wb + (((mt * 16 + l15) * 64 + g * 16) ^ ((l15 & 7) << 4)));
    };

    // ---- phase 1: SINGLE merged q+k+v GEMM pass.
    // acc[mt][0,1]=q, acc[mt][2,3]=k, acc[mt][4,5]=v (96 acc VGPRs, no cap now)
    {
        f32x4 acc[4][6];
        #pragma unroll
        for (int mt = 0; mt < 4; ++mt)
            #pragma unroll
            for (int n6 = 0; n6 < 6; ++n6) acc[mt][n6] = fz;

        #pragma unroll
        for (int ks = 0; ks < 8; ++ks) {
            f16x8 a[4], bb6[6];
            #pragma unroll
            for (int mt = 0; mt < 4; ++mt) {
                int row = mt * 16 + l15;
                a[mt] = *reinterpret_cast<const f16x8*>(
                    L + ((row * 512 + ks * 64 + g * 16) ^ ((row & 7) << 4)));
            }
            #pragma unroll
            for (int p = 0; p < 3; ++p)
                #pragma unroll
                for (int nt = 0; nt < 2; ++nt)
                    bb6[p * 2 + nt] = *reinterpret_cast<const f16x8*>(
                        w_t + ((p << 8) + (h << 5) + nt * 16 + l15) * 256 + ks * 32 + g * 8);
            #pragma unroll
            for (int mt = 0; mt < 4; ++mt)
                #pragma unroll
                for (int n6 = 0; n6 < 6; ++n6)
                    acc[mt][n6] = __builtin_amdgcn_mfma_f32_16x16x32_f16(a[mt], bb6[n6], acc[mt][n6], 0, 0, 0);
        }

        // q epilogue
        {
            f32x4 a0[4], a1[4];
            #pragma unroll
            for (int mt = 0; mt < 4; ++mt) { a0[mt] = acc[mt][0]; a1[mt] = acc[mt][1]; }
            float ls = __expf(fminf(scale[h], LOG100));
            norm_pass(a0, a1, ls, q_bias[(h << 5) + l15], q_bias[(h << 5) + 16 + l15], qa);
        }
        // k epilogue
        {
            f32x4 a0[4], a1[4];
            #pragma unroll
            for (int mt = 0; mt < 4; ++mt) { a0[mt] = acc[mt][2]; a1[mt] = acc[mt][3]; }
            norm_pass(a0, a1, 1.0f, 0.f, 0.f, kb);
        }
        // v epilogue: +bias -> bounce transposed [u 32][pix 64] -> B-frags
        {
            float b0 = v_bias[(h << 5) + l15], b1 = v_bias[(h << 5) + 16 + l15];
            #pragma unroll
            for (int mt = 0; mt < 4; ++mt)
                #pragma unroll
                for (int nt = 0; nt < 2; ++nt) {
                    float bsel = nt ? b1 : b0;
                    f32x4 av = acc[mt][4 + nt];
                    f16x4 pk = { (f16)(av[0] + bsel), (f16)(av[1] + bsel),
                                 (f16)(av[2] + bsel), (f16)(av[3] + bsel) };
                    int u = nt * 16 + l15;
                    int pix0 = mt * 16 + (g << 2);
                    *reinterpret_cast<f16x4*>(wb + ((u * 128 + pix0 * 2) ^ ((u & 7) << 4))) = pk;
                }
            #pragma unroll
            for (int nt = 0; nt < 2; ++nt)
                #pragma unroll
                for (int ks = 0; ks < 2; ++ks)
                    vf[nt][ks] = *reinterpret_cast<const f16x8*>(
                        wb + (((nt * 16 + l15) * 128 + ks * 64 + g * 16) ^ ((l15 & 7) << 4)));
        }
    }

    // ---- phase 2: S + bias (+mask), softmax (1/sum folded into P), pack
    f16x4 ph[4][4];
    #pragma unroll
    for (int mt = 0; mt < 4; ++mt) {
        f32x4 sr[4];
        #pragma unroll
        for (int nt = 0; nt < 4; ++nt)
            sr[nt] = __builtin_amdgcn_mfma_f32_16x16x32_f16(qa[mt], kb[nt], fz, 0, 0, 0);
        #pragma unroll
        for (int nt = 0; nt < 4; ++nt)
            sr[nt] += *reinterpret_cast<const f32x4*>(
                biasfrag + ((((h * 4 + mt) * 4 + nt) * 64 + lane) << 2));
        if (boundary) {
            #pragma unroll
            for (int r = 0; r < 4; ++r) {
                int q = mt * 16 + (g << 2) + r;
                int lq = seg2((wh << 3) + (q >> 3)) * 3 + seg2((ww << 3) + (q & 7));
                #pragma unroll
                for (int nt = 0; nt < 4; ++nt) {
                    int k = nt * 16 + l15;
                    int lk = seg2((wh << 3) + (k >> 3)) * 3 + seg2((ww << 3) + (k & 7));
                    if (lq != lk) sr[nt][r] -= 100.0f;
                }
            }
        }
        #pragma unroll
        for (int r = 0; r < 4; ++r) {
            float mx = fmaxf(fmaxf(sr[0][r], sr[1][r]), fmaxf(sr[2][r], sr[3][r]));
            mx = fmaxf(mx, __shfl_xor(mx, 1));
            mx = fmaxf(mx, __shfl_xor(mx, 2));
            mx = fmaxf(mx, __shfl_xor(mx, 4));
            mx = fmaxf(mx, __shfl_xor(mx, 8));
            float sm = 0.f;
            #pragma unroll
            for (int nt = 0; nt < 4; ++nt) {
                float e = __expf(sr[nt][r] - mx);
                sr[nt][r] = e;
                sm += e;
            }
            sm += __shfl_xor(sm, 1); sm += __shfl_xor(sm, 2);
            sm += __shfl_xor(sm, 4); sm += __shfl_xor(sm, 8);
            float inv = 1.0f / sm;
            #pragma unroll
            for (int nt = 0; nt < 4; ++nt) sr[nt][r] *= inv;
        }
        #pragma unroll
        for (int nt = 0; nt < 4; ++nt)
            ph[mt][nt] = f16x4{ (f16)sr[nt][0], (f16)sr[nt][1], (f16)sr[nt][2], (f16)sr[nt][3] };
    }

    // ---- PV in two 32-key halves via wave-private bounce (P already normalized)
    f32x4 o[4][2];
    #pragma unroll
    for (int mt = 0; mt < 4; ++mt) { o[mt][0] = fz; o[mt][1] = fz; }
    #pragma unroll
    for (int half = 0; half < 2; ++half) {
        #pragma unroll
        for (int mt = 0; mt < 4; ++mt)
            #pragma unroll
            for (int nt2 = 0; nt2 < 2; ++nt2)
                #pragma unroll
                for (int r = 0; r < 4; ++r) {
                    int q = mt * 16 + (g << 2) + r;
                    int key = nt2 * 16 + l15;
                    *reinterpret_cast<f16*>(wb + ((q * 64 + key * 2) ^ ((q & 3) << 4))) =
                        ph[mt][half * 2 + nt2][r];
                }
        #pragma unroll
        for (int mt = 0; mt < 4; ++mt) {
            int q = mt * 16 + l15;
            f16x8 pa = *reinterpret_cast<const f16x8*>(
                wb + ((q * 64 + g * 16) ^ ((q & 3) << 4)));
            #pragma unroll
            for (int nt = 0; nt < 2; ++nt)
                o[mt][nt] = __builtin_amdgcn_mfma_f32_16x16x32_f16(pa, vf[nt][half], o[mt][nt], 0, 0, 0);
        }
    }

    // ---- phase 3: O -> ot (reuse x-tile region), fused proj, direct store
    __syncthreads();   // barrier 2: all waves done reading x-tile
    #pragma unroll
    for (int mt = 0; mt < 4; ++mt)
        #pragma unroll
        for (int r = 0; r < 4; ++r) {
            int q = mt * 16 + (g << 2) + r;
            #pragma unroll
            for (int nt = 0; nt < 2; ++nt) {
                int ch = (h << 5) + nt * 16 + l15;
                *reinterpret_cast<f16*>(L + ((q * 512 + ch * 2) ^ ((q & 7) << 4))) =
                    (f16)o[mt][nt][r];
            }
        }
    __syncthreads();   // barrier 3

    const int c0 = h << 5;
    f32x4 pc[4][2];
    #pragma unroll
    for (int mt = 0; mt < 4; ++mt) { pc[mt][0] = fz; pc[mt][1] = fz; }
    #pragma unroll
    for (int ks = 0; ks < 8; ++ks) {
        f16x8 a[4], bfr[2];
        #pragma unroll
        for (int mt = 0; mt < 4; ++mt) {
            int q = mt * 16 + l15;
            a[mt] = *reinterpret_cast<const f16x8*>(
                L + ((q * 512 + ks * 64 + g * 16) ^ ((q & 7) << 4)));
        }
        #pragma unroll
        for (int nt = 0; nt < 2; ++nt)
            bfr[nt] = *reinterpret_cast<const f16x8*>(
                p_t + (c0 + nt * 16 + l15) * 256 + ks * 32 + g * 8);
        #pragma unroll
        for (int mt = 0; mt < 4; ++mt)
            #pragma unroll
            for (int nt = 0; nt < 2; ++nt)
                pc[mt][nt] = __builtin_amdgcn_mfma_f32_16x16x32_f16(a[mt], bfr[nt], pc[mt][nt], 0, 0, 0);
    }
    float pb0 = proj_b[c0 + l15], pb1 = proj_b[c0 + 16 + l15];
    #pragma unroll
    for (int mt = 0; mt < 4; ++mt)
        #pragma unroll
        for (int r = 0; r < 4; ++r) {
            int q = mt * 16 + (g << 2) + r;
            int i = ((wh << 3) + (q >> 3) + 4) & 255;   // roll(+4) un-partition
            int j = ((ww << 3) + (q & 7) + 4) & 255;
            long addr = (((long)b * 256 + i) * 256 + j) * 256;
            out[addr + c0 + l15]      = pc[mt][0][r] + pb0;
            out[addr + c0 + 16 + l15] = pc[mt][1][r] + pb1;
        }
}

extern "C" void kernel_launch(void* const* d_in, const int* in_sizes, int n_in,
                              void* d_out, int out_size, void* d_ws, size_t ws_size,
                              hipStream_t stream) {
    const float* x      = (const float*)d_in[0];
    const float* qkv_w  = (const float*)d_in[1];
    const float* q_bias = (const float*)d_in[2];
    const float* v_bias = (const float*)d_in[3];
    const float* scale  = (const float*)d_in[4];
    const float* cpb_w1 = (const float*)d_in[5];
    const float* cpb_b1 = (const float*)d_in[6];
    const float* cpb_w2 = (const float*)d_in[7];
    const float* proj_w = (const float*)d_in[8];
    const float* proj_b = (const float*)d_in[9];
    float* out = (float*)d_out;

    char* ws = (char*)d_ws;
    float* biasfrag = (float*)(ws);                         // 128 KiB
    f16* w_t  = (f16*)(ws + 131072);                        // 384 KiB
    f16* p_t  = (f16*)(ws + 524288);                        // 128 KiB

    hipLaunchKernelGGL(k_prep, dim3(129), dim3(512), 0, stream,
                       cpb_w1, cpb_b1, cpb_w2, qkv_w, proj_w, biasfrag, w_t, p_t);
    hipLaunchKernelGGL(k_fused, dim3(2048), dim3(512), 0, stream,
                       x, w_t, q_bias, v_bias, scale, biasfrag, p_t, proj_b, out);
}